// Round 3
// baseline (1197.733 us; speedup 1.0000x reference)
//
#include <hip/hip_runtime.h>
#include <hip/hip_bf16.h>

// Bahdanau additive attention, B=64, S=2048, H=1024 (fp32 in/out).
//   score[b,s] = sum_o v[o] * tanh( (enc[b,s,:].W_h[o,:]) + dp[b,o] )
//   weights = softmax_s(score);  context[b,:] = sum_s weights[b,s]*enc[b,s,:]
//
// R4 (resubmit; R4 never ran): score GEMM upgraded from 128x128 m97-structure
// (~880 TF ceiling) to the 256x256 8-phase schedule (T2 swizzle + T3/T4
// counted vmcnt + T5 setprio): 8 waves (2M x 4N), BK=64, dbuf LDS 128 KiB,
// per-wave 128x64 output. Stage stream: tile t phases issue A0(t+1), A1(t+1),
// B0(t+2), B1(t+2); boundary s_waitcnt vmcnt(4) (counted, never 0 till tail).
//
// d_ws: [0,256KB) dec_proj fp32 [64][1024]; [256KB,2.25MB) W_h bf16;
//       [2.25MB, +256MB) enc bf16 (guarded by ws_size).

#define B_ 64
#define S_ 2048
#define H_ 1024
#define NT_ 16   // K tiles: 1024 / 64

typedef __attribute__((ext_vector_type(8))) short short8;   // 8 bf16
typedef __attribute__((ext_vector_type(4))) float floatx4;  // MFMA acc

__device__ __forceinline__ short f2bf(float f) {
    unsigned u = __float_as_uint(f);
    return (short)((u + 0x7FFFu + ((u >> 16) & 1u)) >> 16);  // RTNE
}
__device__ __forceinline__ unsigned pk2bf(float a, float b) {  // low=a, high=b
    unsigned ua = __float_as_uint(a), ub = __float_as_uint(b);
    ua = (ua + 0x7FFFu + ((ua >> 16) & 1u)) >> 16;
    ub = (ub + 0x7FFFu + ((ub >> 16) & 1u)) & 0xFFFF0000u;
    return ua | ub;
}
__device__ __forceinline__ void gload_lds16(const void* g, void* l) {
    __builtin_amdgcn_global_load_lds(
        (const __attribute__((address_space(1))) unsigned*)g,
        (__attribute__((address_space(3))) unsigned*)l, 16, 0, 0);
}

// ---------------- zero the score region (atomicAdd target) ----------------
__global__ __launch_bounds__(256) void zero_score_kernel(float* __restrict__ sc) {
    ((float4*)sc)[blockIdx.x * 256 + threadIdx.x] = make_float4(0.f, 0.f, 0.f, 0.f);
}

// ---------------- dec_proj[b,o] = sum_h dec[b,h] * W_s[o,h] ----------------
__global__ __launch_bounds__(256) void dec_proj_kernel(
        const float* __restrict__ dec, const float* __restrict__ Ws,
        float* __restrict__ dp) {
    __shared__ float sdec[H_];
    const int b = blockIdx.y;
    const int o = blockIdx.x * 256 + threadIdx.x;
    ((float4*)sdec)[threadIdx.x] = ((const float4*)(dec + b * H_))[threadIdx.x];
    __syncthreads();
    const float4* wr = (const float4*)(Ws + (size_t)o * H_);
    float acc = 0.f;
#pragma unroll 4
    for (int i = 0; i < H_ / 4; ++i) {
        float4 wv = wr[i];
        acc += sdec[4*i+0]*wv.x + sdec[4*i+1]*wv.y + sdec[4*i+2]*wv.z + sdec[4*i+3]*wv.w;
    }
    dp[b * H_ + o] = acc;
}

// ---------------- W_h fp32 -> bf16 ----------------
__global__ __launch_bounds__(256) void cvt_wh_kernel(
        const float* __restrict__ Wh, short* __restrict__ Wbf) {
    const int i = blockIdx.x * 256 + threadIdx.x;
    float4 f = ((const float4*)Wh)[i];
    *(short4*)&Wbf[i * 4] = make_short4(f2bf(f.x), f2bf(f.y), f2bf(f.z), f2bf(f.w));
}

// ---------------- enc fp32 -> bf16 (grid-stride, 32B/thread/iter) ----------------
__global__ __launch_bounds__(256) void cvt_enc_kernel(
        const float* __restrict__ enc, short* __restrict__ out) {
    const size_t total = (size_t)B_ * S_ * H_ / 8;
    for (size_t c = (size_t)blockIdx.x * 256 + threadIdx.x; c < total;
         c += (size_t)gridDim.x * 256) {
        const float4* p = (const float4*)enc + c * 2;
        float4 f0 = p[0], f1 = p[1];
        union { short8 s; unsigned u[4]; } cv;
        cv.u[0] = pk2bf(f0.x, f0.y);
        cv.u[1] = pk2bf(f0.z, f0.w);
        cv.u[2] = pk2bf(f1.x, f1.y);
        cv.u[3] = pk2bf(f1.z, f1.w);
        ((short8*)out)[c] = cv.s;
    }
}

// ================= 256x256 8-phase fused score GEMM =================
// grid = (M/256)*(N/256) = 512*4; mtile = bid>>2, nb = bid&3.
// LDS: As/Bs [2 dbuf][2 half][128 rows][64 k] bf16 = 64 KiB each, 128 KiB total.
// Staging (per half-tile = 2 gload_lds/thread): chunk c = r*512+tid;
// row = c>>3, c8 = c&7, global chunk g = c8 ^ (row&7) (XOR swizzle on the
// global side, LDS linear -- Guideline 21).
#define STAGEA(bufp, half, ktile) do {                                          \
    gload_lds16(gA + (size_t)(half) * (128 * H_) + (ktile) * 64,                \
                &As[(bufp)][(half)][wave * 512]);                               \
    gload_lds16(gA + (size_t)(half) * (128 * H_) + (ktile) * 64 + 64 * H_,      \
                &As[(bufp)][(half)][4096 + wave * 512]);                        \
} while (0)
#define STAGEB(bufp, half, ktile) do {                                          \
    gload_lds16(gB + (size_t)(half) * (128 * H_) + (ktile) * 64,                \
                &Bs[(bufp)][(half)][wave * 512]);                               \
    gload_lds16(gB + (size_t)(half) * (128 * H_) + (ktile) * 64 + 64 * H_,      \
                &Bs[(bufp)][(half)][4096 + wave * 512]);                        \
} while (0)

#define MFMA16(I0) do {                                                         \
    _Pragma("unroll")                                                           \
    for (int kt = 0; kt < 2; ++kt) {                                            \
        _Pragma("unroll")                                                       \
        for (int j = 0; j < 4; ++j) {                                           \
            acc[I0][j]     = __builtin_amdgcn_mfma_f32_16x16x32_bf16(           \
                                 af[0][kt], bfr[kt][j], acc[I0][j], 0, 0, 0);   \
            acc[(I0)+1][j] = __builtin_amdgcn_mfma_f32_16x16x32_bf16(           \
                                 af[1][kt], bfr[kt][j], acc[(I0)+1][j], 0, 0, 0); \
        }                                                                       \
    }                                                                           \
} while (0)

// phase = {ds_read subtile; issue stage; barrier; lgkmcnt(0); setprio(1);
//          16 MFMA; setprio(0); [tail vmcnt]; barrier}
#define PHASE(I0, STG, TAILWAIT) do {                                           \
    _Pragma("unroll")                                                           \
    for (int ii = 0; ii < 2; ++ii)                                              \
        _Pragma("unroll")                                                       \
        for (int kt = 0; kt < 2; ++kt)                                          \
            af[ii][kt] = *(const short8*)(aBase + ((I0) + ii) * 1024 +          \
                                          (((kt * 4 + quad) ^ swz) * 8));       \
    STG;                                                                        \
    __builtin_amdgcn_s_barrier();                                               \
    asm volatile("s_waitcnt lgkmcnt(0)" ::: "memory");                          \
    __builtin_amdgcn_s_setprio(1);                                              \
    MFMA16(I0);                                                                 \
    __builtin_amdgcn_s_setprio(0);                                              \
    TAILWAIT;                                                                   \
    __builtin_amdgcn_s_barrier();                                               \
} while (0)

__global__ __launch_bounds__(512, 2) void score256_kernel(
        const short* __restrict__ encbf, const short* __restrict__ Wbf,
        const float* __restrict__ dp, const float* __restrict__ v,
        float* __restrict__ score) {
    __shared__ short As[2][2][128 * 64];   // 64 KiB
    __shared__ short Bs[2][2][128 * 64];   // 64 KiB

    const int tid  = threadIdx.x;
    const int wave = tid >> 6;
    const int lane = tid & 63;
    const int l15  = lane & 15;
    const int quad = lane >> 4;
    const int wy   = wave & 1;        // m-half (128 rows)
    const int wx   = wave >> 1;       // n-quarter (64 cols)

    const int mtile = blockIdx.x >> 2;
    const int nb    = blockIdx.x & 3;
    const int m0    = mtile * 256;
    const int n0    = nb * 256;
    const int b     = m0 >> 11;       // 8 M-tiles per batch, no straddle
    const int swz   = l15 & 7;

    const int rr0 = tid >> 3;                       // staging row (0..63)
    const int g8  = (tid & 7) ^ (rr0 & 7);          // swizzled global chunk
    const short* gA = encbf + (size_t)(m0 + rr0) * H_ + g8 * 8;
    const short* gB = Wbf   + (size_t)(n0 + rr0) * H_ + g8 * 8;

    floatx4 acc[8][4];
#pragma unroll
    for (int i = 0; i < 8; ++i)
#pragma unroll
        for (int j = 0; j < 4; ++j) acc[i][j] = (floatx4){0.f, 0.f, 0.f, 0.f};

    short8 af[2][2];
    short8 bfr[2][4];

    // prologue: tile0 fully + tile1 B halves; retire tile0 (vmcnt(4) leaves
    // B(1) in flight)
    STAGEA(0, 0, 0); STAGEA(0, 1, 0);
    STAGEB(0, 0, 0); STAGEB(0, 1, 0);
    STAGEB(1, 0, 1); STAGEB(1, 1, 1);
    asm volatile("s_waitcnt vmcnt(4)" ::: "memory");
    __builtin_amdgcn_s_barrier();

#pragma unroll 1
    for (int t = 0; t < NT_; ++t) {
        const int buf = t & 1;
        const short* aBase = &As[buf][wy][0] + l15 * 64;
        const short* bBase = &Bs[buf][wx >> 1][0] + ((wx & 1) * 64 + l15) * 64;

        // B-frags for the whole tile (read once, register-resident)
#pragma unroll
        for (int kt = 0; kt < 2; ++kt)
#pragma unroll
            for (int j = 0; j < 4; ++j)
                bfr[kt][j] = *(const short8*)(bBase + j * 1024 +
                                              (((kt * 4 + quad) ^ swz) * 8));

        PHASE(0, { if (t + 1 < NT_) STAGEA(buf ^ 1, 0, t + 1); }, (void)0);
        PHASE(2, { if (t + 1 < NT_) STAGEA(buf ^ 1, 1, t + 1); }, (void)0);
        PHASE(4, { if (t + 2 < NT_) STAGEB(buf, 0, t + 2); }, (void)0);
        PHASE(6, { if (t + 2 < NT_) STAGEB(buf, 1, t + 2); },
              { if (t < NT_ - 2) { asm volatile("s_waitcnt vmcnt(4)" ::: "memory"); }
                else             { asm volatile("s_waitcnt vmcnt(0)" ::: "memory"); } });
    }

    // ---- fused epilogue: +dp, tanh, *v, reduce over block's 256 cols ----
    float part[8][4];
#pragma unroll
    for (int i = 0; i < 8; ++i)
#pragma unroll
        for (int r = 0; r < 4; ++r) part[i][r] = 0.f;

#pragma unroll
    for (int j = 0; j < 4; ++j) {
        const int o = n0 + wx * 64 + j * 16 + l15;
        const float dpv = dp[b * H_ + o];
        const float vv  = v[o];
#pragma unroll
        for (int i = 0; i < 8; ++i)
#pragma unroll
            for (int r = 0; r < 4; ++r) {
                float x = acc[i][j][r] + dpv;          // D[row=quad*4+r][col=l15]
                x = fminf(10.f, fmaxf(-10.f, x));
                float e = __expf(x + x);               // e^(2x)
                float t = 1.f - 2.f * __builtin_amdgcn_rcpf(e + 1.f);
                part[i][r] += t * vv;
            }
    }
#pragma unroll
    for (int i = 0; i < 8; ++i)
#pragma unroll
        for (int r = 0; r < 4; ++r) {
            float s = part[i][r];
            s += __shfl_xor(s, 1, 64);
            s += __shfl_xor(s, 2, 64);
            s += __shfl_xor(s, 4, 64);
            s += __shfl_xor(s, 8, 64);
            if (l15 == 0)   // lanes 0/16/32/48 hold rows quad*4+r of frag i
                atomicAdd(&score[m0 + wy * 128 + i * 16 + quad * 4 + r], s);
        }
}

// ---------------- fallback 128x128 score GEMM (reg-staged A, fp32 enc) ----------------
__global__ __launch_bounds__(256, 3) void score_kernel_fb(
        const float* __restrict__ enc, const short* __restrict__ Wbf,
        const float* __restrict__ dp, const float* __restrict__ v,
        float* __restrict__ score) {
    __shared__ short As[128 * 64];
    __shared__ short Bs[128 * 64];

    const int tid  = threadIdx.x;
    const int wave = tid >> 6;
    const int lane = tid & 63;
    const int l15  = lane & 15;
    const int quad = lane >> 4;
    const int wy   = wave & 1;
    const int wx   = wave >> 1;

    const int mtile = blockIdx.x >> 3;
    const int nb    = blockIdx.x & 7;
    const int m0    = mtile * 128;
    const int n0    = nb * 128;
    const int b     = m0 >> 11;

    floatx4 acc[4][4];
#pragma unroll
    for (int i = 0; i < 4; ++i)
#pragma unroll
        for (int j = 0; j < 4; ++j) acc[i][j] = (floatx4){0.f, 0.f, 0.f, 0.f};

    const short* aLds = As + (wy * 64 + l15) * 64;
    const short* bLds = Bs + (wx * 64 + l15) * 64;
    const int swz = l15 & 7;
    const int srow = tid >> 3;
    const int bc   = tid & 7;

    for (int k0 = 0; k0 < H_; k0 += 64) {
#pragma unroll
        for (int r = 0; r < 4; ++r) {
            const int n = r * 32 + srow;
            const int g = bc ^ (n & 7);
            const short* gp = Wbf + (size_t)(n0 + n) * H_ + k0 + g * 8;
            gload_lds16(gp, (void*)(Bs + (r * 256 + wave * 64) * 8));
        }
#pragma unroll
        for (int i = 0; i < 4; ++i) {
            const int La = i * 256 + tid;
            const int m  = La >> 3;
            const int c8 = La & 7;
            const float4* gp = (const float4*)(enc + (size_t)(m0 + m) * H_ + k0 + c8 * 8);
            float4 f0 = gp[0], f1 = gp[1];
            union { short8 s; unsigned u[4]; } cv;
            cv.u[0] = pk2bf(f0.x, f0.y);
            cv.u[1] = pk2bf(f0.z, f0.w);
            cv.u[2] = pk2bf(f1.x, f1.y);
            cv.u[3] = pk2bf(f1.z, f1.w);
            *(short8*)&As[m * 64 + (c8 ^ (m & 7)) * 8] = cv.s;
        }
        __syncthreads();
#pragma unroll
        for (int kt = 0; kt < 2; ++kt) {
            short8 a2[4], b2[4];
#pragma unroll
            for (int i = 0; i < 4; ++i)
                a2[i] = *(const short8*)(aLds + i * 16 * 64 + (((kt * 4 + quad) ^ swz) * 8));
#pragma unroll
            for (int j = 0; j < 4; ++j)
                b2[j] = *(const short8*)(bLds + j * 16 * 64 + (((kt * 4 + quad) ^ swz) * 8));
#pragma unroll
            for (int i = 0; i < 4; ++i)
#pragma unroll
                for (int j = 0; j < 4; ++j)
                    acc[i][j] = __builtin_amdgcn_mfma_f32_16x16x32_bf16(a2[i], b2[j], acc[i][j], 0, 0, 0);
        }
        __syncthreads();
    }

    float part[4][4];
#pragma unroll
    for (int i = 0; i < 4; ++i)
#pragma unroll
        for (int r = 0; r < 4; ++r) part[i][r] = 0.f;
#pragma unroll
    for (int j = 0; j < 4; ++j) {
        const int o = n0 + wx * 64 + j * 16 + l15;
        const float dpv = dp[b * H_ + o];
        const float vv  = v[o];
#pragma unroll
        for (int i = 0; i < 4; ++i)
#pragma unroll
            for (int r = 0; r < 4; ++r) {
                float x = acc[i][j][r] + dpv;
                x = fminf(10.f, fmaxf(-10.f, x));
                float e = __expf(x + x);
                float t = 1.f - 2.f * __builtin_amdgcn_rcpf(e + 1.f);
                part[i][r] += t * vv;
            }
    }
#pragma unroll
    for (int i = 0; i < 4; ++i)
#pragma unroll
        for (int r = 0; r < 4; ++r) {
            float s = part[i][r];
            s += __shfl_xor(s, 1, 64);
            s += __shfl_xor(s, 2, 64);
            s += __shfl_xor(s, 4, 64);
            s += __shfl_xor(s, 8, 64);
            if (l15 == 0)
                atomicAdd(&score[m0 + wy * 64 + i * 16 + quad * 4 + r], s);
        }
}

// ---------------- softmax over S in-place + zero context ----------------
__global__ __launch_bounds__(256) void softmax_kernel(float* __restrict__ out) {
    const int b = blockIdx.x;
    const int tid = threadIdx.x;
    float* sc = out + B_ * H_ + b * S_;

    ((float4*)(out + b * H_))[tid] = make_float4(0.f, 0.f, 0.f, 0.f);

    float xs[8];
    float m = -1e30f;
#pragma unroll
    for (int i = 0; i < 8; ++i) { xs[i] = sc[tid + i * 256]; m = fmaxf(m, xs[i]); }
#pragma unroll
    for (int off = 32; off > 0; off >>= 1) m = fmaxf(m, __shfl_xor(m, off, 64));
    __shared__ float redm[4];
    const int wv = tid >> 6;
    if ((tid & 63) == 0) redm[wv] = m;
    __syncthreads();
    m = fmaxf(fmaxf(redm[0], redm[1]), fmaxf(redm[2], redm[3]));

    float s = 0.f;
#pragma unroll
    for (int i = 0; i < 8; ++i) { xs[i] = __expf(xs[i] - m); s += xs[i]; }
#pragma unroll
    for (int off = 32; off > 0; off >>= 1) s += __shfl_xor(s, off, 64);
    __shared__ float reds[4];
    if ((tid & 63) == 0) reds[wv] = s;
    __syncthreads();
    s = reds[0] + reds[1] + reds[2] + reds[3];

    const float inv = 1.f / s;
#pragma unroll
    for (int i = 0; i < 8; ++i) sc[tid + i * 256] = xs[i] * inv;
}

// ---------------- context[b,h] = sum_s weights[b,s] * enc[b,s,h] ----------------
__global__ __launch_bounds__(256) void context_kernel(
        const float* __restrict__ enc, const float* __restrict__ wts,
        float* __restrict__ ctx) {
    const int b    = blockIdx.x;
    const int scnk = blockIdx.y;
    const int t    = threadIdx.x;
    const float* w  = wts + b * S_ + scnk * 256;
    const float4* e = (const float4*)(enc + ((long)b * S_ + scnk * 256) * H_);
    float4 acc = make_float4(0.f, 0.f, 0.f, 0.f);
#pragma unroll 4
    for (int s = 0; s < 256; ++s) {
        const float ww = w[s];
        const float4 ev = e[s * (H_ / 4) + t];
        acc.x = fmaf(ww, ev.x, acc.x);
        acc.y = fmaf(ww, ev.y, acc.y);
        acc.z = fmaf(ww, ev.z, acc.z);
        acc.w = fmaf(ww, ev.w, acc.w);
    }
    float* c = ctx + b * H_ + t * 4;
    atomicAdd(c + 0, acc.x);
    atomicAdd(c + 1, acc.y);
    atomicAdd(c + 2, acc.z);
    atomicAdd(c + 3, acc.w);
}

extern "C" void kernel_launch(void* const* d_in, const int* in_sizes, int n_in,
                              void* d_out, int out_size, void* d_ws, size_t ws_size,
                              hipStream_t stream) {
    const float* dec = (const float*)d_in[0];   // [64,1,1024]
    const float* enc = (const float*)d_in[1];   // [64,2048,1024]
    const float* Wh  = (const float*)d_in[2];   // [1024,1024]
    const float* Ws  = (const float*)d_in[3];   // [1024,1024]
    const float* v   = (const float*)d_in[4];   // [1024]

    float* out = (float*)d_out;
    float* ctx = out;                 // [64*1024] context
    float* wts = out + B_ * H_;       // [64*2048] scores -> weights (in place)

    float* dp  = (float*)d_ws;                                      // 256 KB
    short* Wbf = (short*)((char*)d_ws + (size_t)B_ * H_ * 4);       // 2 MB bf16
    const size_t base = (size_t)B_ * H_ * 4 + (size_t)H_ * H_ * 2;  // 2.25 MB
    const size_t enc_need = (size_t)B_ * S_ * H_ * 2;               // 256 MB
    short* encbf = (ws_size >= base + enc_need)
                       ? (short*)((char*)d_ws + base) : nullptr;
    (void)in_sizes; (void)n_in; (void)out_size;

    zero_score_kernel<<<(B_ * S_ / 4) / 256, 256, 0, stream>>>(wts);
    dec_proj_kernel<<<dim3(H_ / 256, B_), 256, 0, stream>>>(dec, Ws, dp);
    cvt_wh_kernel<<<(H_ * H_ / 4) / 256, 256, 0, stream>>>(Wh, Wbf);
    if (encbf) {
        cvt_enc_kernel<<<8192, 256, 0, stream>>>(enc, encbf);
        score256_kernel<<<(B_ * S_ / 256) * (H_ / 256), 512, 0, stream>>>(
            encbf, Wbf, dp, v, wts);
    } else {
        score_kernel_fb<<<(B_ * S_ / 128) * (H_ / 128), 256, 0, stream>>>(
            enc, Wbf, dp, v, wts);
    }
    softmax_kernel<<<B_, 256, 0, stream>>>(out);
    context_kernel<<<dim3(B_, S_ / 256), 256, 0, stream>>>(enc, wts, ctx);
}